// Round 19
// baseline (283.199 us; speedup 1.0000x reference)
//
#include <hip/hip_runtime.h>
#include <math.h>

// GaussianGenerator v17b: conv3 xm-build vectorized via transposed g3 in LDS
// (fix: g3T load is a 384-stride loop covering all 400 elements).
// conv1=v16, conv2=v15 frozen, MLP=32-row. All fp32.

__device__ __forceinline__ float eluf(float v) { return v > 0.f ? v : __expf(v) - 1.f; }

#define NLOG2E_HALF (-0.72134752f)   // -0.5*log2(e)

#define FMA4(A, S, V) \
  A.x = fmaf(S, V.x, A.x); A.y = fmaf(S, V.y, A.y); \
  A.z = fmaf(S, V.z, A.z); A.w = fmaf(S, V.w, A.w);

// ---------------- conv1: n=5, fin=64, K=25, cout=160; 2 graphs/block ----------------
__global__ __launch_bounds__(512) void conv1_kernel(
    const float* __restrict__ x, const float* __restrict__ pos,
    const float* __restrict__ g, const float* __restrict__ mu, const float* __restrict__ sig,
    const float* __restrict__ root, const float* __restrict__ bias,
    float* __restrict__ xout)
{
  const int b = blockIdx.x, tid = threadIdx.x;
  __shared__ __align__(16) float s_xT[64 * 12];
  __shared__ __align__(16) float s_xm[10 * 832];
  __shared__ __align__(16) float s_w[2 * 5 * 5 * 28];
  __shared__ __align__(16) float s_red[2 * 2 * 5 * 160];
  __shared__ float s_pos[20];
  __shared__ float s_msc[25][4];
  __shared__ float s_ideg[10];

  if (tid < 20) s_pos[tid] = pos[b * 20 + tid];
  if (tid < 25) {
    float m0 = mu[2 * tid], m1 = mu[2 * tid + 1];
    float s0 = sig[2 * tid], s1 = sig[2 * tid + 1];
    s_msc[tid][0] = 0.5f - m0;
    s_msc[tid][1] = 0.5f - m1;
    s_msc[tid][2] = NLOG2E_HALF / (s0 * s0 + 1e-15f);
    s_msc[tid][3] = NLOG2E_HALF / (s1 * s1 + 1e-15f);
  }
  for (int e = tid; e < 640; e += 512) { int nd = e >> 6, i = e & 63; s_xT[i * 12 + nd] = x[b * 640 + nd * 64 + i]; }
  for (int e = tid; e < 320; e += 512) { int r = e / 32, c = e % 32; s_xm[r * 832 + 800 + c] = 0.f; }
  __syncthreads();

  if (tid < 10) {
    int gg = tid / 5, t = tid % 5, c = 0;
    for (int s = 0; s < 5; ++s) {
      if (s == t) continue;
      float d0 = s_pos[(gg * 5 + t) * 2]     - s_pos[(gg * 5 + s) * 2]     + 1e-12f;
      float d1 = s_pos[(gg * 5 + t) * 2 + 1] - s_pos[(gg * 5 + s) * 2 + 1] + 1e-12f;
      c += (d0 * d0 + d1 * d1 < 0.25f) ? 1 : 0;
    }
    s_ideg[tid] = 1.f / (float)(c < 1 ? 1 : c);
  }
  for (int e = tid; e < 1400; e += 512) {
    int gg = e / 700, r2 = e % 700, t = r2 / 140, c = r2 % 140;
    int ch = c / 28, skl = c % 28;
    float wv = 0.f;
    if (skl < 25) {
      int kk = skl / 5, s = skl % 5, k = ch * 5 + kk;
      float d0 = s_pos[(gg * 5 + t) * 2]     - s_pos[(gg * 5 + s) * 2];
      float d1 = s_pos[(gg * 5 + t) * 2 + 1] - s_pos[(gg * 5 + s) * 2 + 1];
      float e0 = d0 + 1e-12f, e1 = d1 + 1e-12f;
      bool m = (e0 * e0 + e1 * e1 < 0.25f) && (s != t);
      float q0 = fmaf(2.f, d0, s_msc[k][0]);
      float q1 = fmaf(2.f, d1, s_msc[k][1]);
      float a = q0 * q0 * s_msc[k][2];
      a = fmaf(q1 * q1, s_msc[k][3], a);
      wv = m ? exp2f(a) : 0.f;
    }
    s_w[e] = wv;
  }
  __syncthreads();

  float sacc[5][2];
  #pragma unroll
  for (int t = 0; t < 5; ++t) { sacc[t][0] = 0.f; sacc[t][1] = 0.f; }
  const int sg = tid / 160, sr = tid % 160, sks = sr / 80, sob = sr % 80;
  const int so0 = sob * 2;

  for (int ch = 0; ch < 5; ++ch) {
    if (tid < 400) {
      const int c0 = tid * 2;
      const float* gp = g + ch * 800 + c0;
      float a[10][2];
      #pragma unroll
      for (int r = 0; r < 10; ++r) { a[r][0] = 0.f; a[r][1] = 0.f; }
      #pragma unroll 4
      for (int i = 0; i < 64; ++i) {
        float2 gv = *(const float2*)(gp + i * 4000);
        float4 xa = *(const float4*)&s_xT[i * 12];
        float4 xb = *(const float4*)&s_xT[i * 12 + 4];
        float2 xc = *(const float2*)&s_xT[i * 12 + 8];
        a[0][0] = fmaf(xa.x, gv.x, a[0][0]); a[0][1] = fmaf(xa.x, gv.y, a[0][1]);
        a[1][0] = fmaf(xa.y, gv.x, a[1][0]); a[1][1] = fmaf(xa.y, gv.y, a[1][1]);
        a[2][0] = fmaf(xa.z, gv.x, a[2][0]); a[2][1] = fmaf(xa.z, gv.y, a[2][1]);
        a[3][0] = fmaf(xa.w, gv.x, a[3][0]); a[3][1] = fmaf(xa.w, gv.y, a[3][1]);
        a[4][0] = fmaf(xb.x, gv.x, a[4][0]); a[4][1] = fmaf(xb.x, gv.y, a[4][1]);
        a[5][0] = fmaf(xb.y, gv.x, a[5][0]); a[5][1] = fmaf(xb.y, gv.y, a[5][1]);
        a[6][0] = fmaf(xb.z, gv.x, a[6][0]); a[6][1] = fmaf(xb.z, gv.y, a[6][1]);
        a[7][0] = fmaf(xb.w, gv.x, a[7][0]); a[7][1] = fmaf(xb.w, gv.y, a[7][1]);
        a[8][0] = fmaf(xc.x, gv.x, a[8][0]); a[8][1] = fmaf(xc.x, gv.y, a[8][1]);
        a[9][0] = fmaf(xc.y, gv.x, a[9][0]); a[9][1] = fmaf(xc.y, gv.y, a[9][1]);
      }
      #pragma unroll
      for (int r = 0; r < 10; ++r)
        *(float2*)&s_xm[r * 832 + c0] = make_float2(a[r][0], a[r][1]);
    }
    __syncthreads();
    if (tid < 320) {
#define C1_STEP(SK0) { \
      float2 m0 = *(const float2*)&s_xm[(sg * 5 + ((SK0) % 5)) * 832 + ((SK0) / 5) * 160 + so0]; \
      float2 m1 = *(const float2*)&s_xm[(sg * 5 + (((SK0) + 1) % 5)) * 832 + (((SK0) + 1) / 5) * 160 + so0]; \
      float2 m2 = *(const float2*)&s_xm[(sg * 5 + (((SK0) + 2) % 5)) * 832 + (((SK0) + 2) / 5) * 160 + so0]; \
      float2 m3 = *(const float2*)&s_xm[(sg * 5 + (((SK0) + 3) % 5)) * 832 + (((SK0) + 3) / 5) * 160 + so0]; \
      _Pragma("unroll") \
      for (int t = 0; t < 5; ++t) { \
        const float4 wv = *(const float4*)&s_w[((sg * 5 + t) * 5 + ch) * 28 + (SK0)]; \
        sacc[t][0] = fmaf(wv.x, m0.x, sacc[t][0]); sacc[t][1] = fmaf(wv.x, m0.y, sacc[t][1]); \
        sacc[t][0] = fmaf(wv.y, m1.x, sacc[t][0]); sacc[t][1] = fmaf(wv.y, m1.y, sacc[t][1]); \
        sacc[t][0] = fmaf(wv.z, m2.x, sacc[t][0]); sacc[t][1] = fmaf(wv.z, m2.y, sacc[t][1]); \
        sacc[t][0] = fmaf(wv.w, m3.x, sacc[t][0]); sacc[t][1] = fmaf(wv.w, m3.y, sacc[t][1]); \
      } }
      if (sks == 0) { C1_STEP(0) C1_STEP(4) C1_STEP(8) C1_STEP(12) }
      else          { C1_STEP(16) C1_STEP(20) C1_STEP(24) }
#undef C1_STEP
    }
    __syncthreads();
  }

  if (tid < 400) {
    const int rb = tid / 80, cb = tid % 80;
    const int r0 = rb * 2, c0 = cb * 2;
    float a00 = 0.f, a01 = 0.f, a10 = 0.f, a11 = 0.f;
    #pragma unroll 4
    for (int i = 0; i < 64; ++i) {
      float2 rv = *(const float2*)(root + i * 160 + c0);
      float2 xv = *(const float2*)&s_xT[i * 12 + r0];
      a00 = fmaf(xv.x, rv.x, a00); a01 = fmaf(xv.x, rv.y, a01);
      a10 = fmaf(xv.y, rv.x, a10); a11 = fmaf(xv.y, rv.y, a11);
    }
    *(float2*)&s_xm[r0 * 832 + c0]       = make_float2(a00, a01);
    *(float2*)&s_xm[(r0 + 1) * 832 + c0] = make_float2(a10, a11);
  }
  if (tid < 320) {
    #pragma unroll
    for (int t = 0; t < 5; ++t) {
      s_red[((sks * 2 + sg) * 5 + t) * 160 + so0]     = sacc[t][0];
      s_red[((sks * 2 + sg) * 5 + t) * 160 + so0 + 1] = sacc[t][1];
    }
  }
  __syncthreads();
  if (tid < 400) {
    const int gg = tid / 200, r2 = tid % 200, t = r2 / 40, oe = (r2 % 40) * 4;
    float4 p0 = *(const float4*)&s_red[((0 + gg) * 5 + t) * 160 + oe];
    float4 p1 = *(const float4*)&s_red[((2 + gg) * 5 + t) * 160 + oe];
    float4 rt = *(const float4*)&s_xm[(gg * 5 + t) * 832 + oe];
    float4 bv = *(const float4*)&bias[oe];
    float idg = s_ideg[gg * 5 + t];
    float4 v;
    v.x = fmaf(p0.x + p1.x, idg, rt.x + bv.x);
    v.y = fmaf(p0.y + p1.y, idg, rt.y + bv.y);
    v.z = fmaf(p0.z + p1.z, idg, rt.z + bv.z);
    v.w = fmaf(p0.w + p1.w, idg, rt.w + bv.w);
    *(float4*)&xout[b * 1600 + (gg * 5 + t) * 160 + oe] =
        make_float4(eluf(v.x), eluf(v.y), eluf(v.z), eluf(v.w));
  }
}

// ---------------- conv2 v15 (frozen): v4 + root-GEMM mini-phase ----------------
__global__ __launch_bounds__(320) void conv2_kernel(
    const float* __restrict__ x, const float* __restrict__ pos,
    const float* __restrict__ g, const float* __restrict__ mu, const float* __restrict__ sig,
    const float* __restrict__ root, const float* __restrict__ bias,
    float* __restrict__ xout)
{
  const int b = blockIdx.x, tid = threadIdx.x;
  __shared__ __align__(16) float s_xT[32 * 28];
  __shared__ __align__(16) float s_xm[125 * 52];
  __shared__ __align__(16) float s_w[25 * 132];
  __shared__ __align__(8)  float2 s_u[25 * 26];
  __shared__ float s_ek[25 * 5];
  __shared__ float s_ideg[25];

  const float* posb = pos + b * 50;
  if (tid < 25) {
    float m0 = mu[2 * tid], m1 = mu[2 * tid + 1];
    float sg0 = sig[2 * tid], sg1 = sig[2 * tid + 1];
    float n0 = NLOG2E_HALF / (sg0 * sg0 + 1e-15f);
    float n1 = NLOG2E_HALF / (sg1 * sg1 + 1e-15f);
    float c0 = 0.5f - m0, c1 = 0.5f - m1;
    s_ek[tid * 5 + 0] = n0;
    s_ek[tid * 5 + 1] = n1;
    s_ek[tid * 5 + 2] = 2.f * n0 * c0;
    s_ek[tid * 5 + 3] = 2.f * n1 * c1;
    s_ek[tid * 5 + 4] = fmaf(n0, c0 * c0, n1 * c1 * c1);
  }
  for (int e = tid; e < 800; e += 320) { int r = e / 32, i = e % 32; s_xT[i * 28 + r] = x[b * 800 + e]; }
  __syncthreads();

  for (int e = tid; e < 625; e += 320) {
    int t = e / 25, s = e % 25;
    float d0 = posb[t * 2]     - posb[s * 2];
    float d1 = posb[t * 2 + 1] - posb[s * 2 + 1];
    float e0 = d0 + 1e-12f, e1 = d1 + 1e-12f;
    bool m = (e0 * e0 + e1 * e1 < 0.25f) && (s != t);
    s_u[t * 26 + s] = m ? make_float2(2.f * d0, 2.f * d1) : make_float2(1e18f, 0.f);
  }
  if (tid < 25) {
    int t = tid, c = 0;
    for (int s = 0; s < 25; ++s) {
      if (s == t) continue;
      float d0 = posb[t * 2]     - posb[s * 2]     + 1e-12f;
      float d1 = posb[t * 2 + 1] - posb[s * 2 + 1] + 1e-12f;
      c += (d0 * d0 + d1 * d1 < 0.25f) ? 1 : 0;
    }
    s_ideg[t] = 1.f / (float)(c < 1 ? 1 : c);
  }
  __syncthreads();

  const bool act = tid < 300;
  const int grp = tid / 60, rr = tid % 60, tg = rr / 12, og = rr % 12;
  const int o0 = og * 4;
  const int t0 = tg * 5, sk0 = grp * 25, s0 = tg * 5;

  float acc2[5][4];
  #pragma unroll
  for (int tt = 0; tt < 5; ++tt) { acc2[tt][0] = acc2[tt][1] = acc2[tt][2] = acc2[tt][3] = 0.f; }

  for (int ch = 0; ch < 5; ++ch) {
    const int k0 = ch * 5;
    for (int e = tid; e < 3125; e += 320) {
      int t = e / 125, c = e % 125;
      int kk = c / 25, s = c % 25, k = k0 + kk;
      float2 uv = s_u[t * 26 + s];
      const float* ekp = &s_ek[k * 5];
      float ar = fmaf(uv.x * uv.x, ekp[0],
                 fmaf(uv.y * uv.y, ekp[1],
                 fmaf(uv.x, ekp[2],
                 fmaf(uv.y, ekp[3], ekp[4]))));
      s_w[t * 132 + c] = exp2f(ar);
    }
    if (act) {
      const float* gp = g + (k0 + grp) * 48 + o0;
      float a[5][4];
      #pragma unroll
      for (int r = 0; r < 5; ++r) { a[r][0] = a[r][1] = a[r][2] = a[r][3] = 0.f; }
      #pragma unroll 4
      for (int i = 0; i < 32; ++i) {
        float4 gv = *(const float4*)(gp + i * 1200);
        float x0 = s_xT[i * 28 + s0];
        float x1 = s_xT[i * 28 + s0 + 1];
        float x2 = s_xT[i * 28 + s0 + 2];
        float x3 = s_xT[i * 28 + s0 + 3];
        float x4 = s_xT[i * 28 + s0 + 4];
        a[0][0] = fmaf(x0, gv.x, a[0][0]); a[0][1] = fmaf(x0, gv.y, a[0][1]);
        a[0][2] = fmaf(x0, gv.z, a[0][2]); a[0][3] = fmaf(x0, gv.w, a[0][3]);
        a[1][0] = fmaf(x1, gv.x, a[1][0]); a[1][1] = fmaf(x1, gv.y, a[1][1]);
        a[1][2] = fmaf(x1, gv.z, a[1][2]); a[1][3] = fmaf(x1, gv.w, a[1][3]);
        a[2][0] = fmaf(x2, gv.x, a[2][0]); a[2][1] = fmaf(x2, gv.y, a[2][1]);
        a[2][2] = fmaf(x2, gv.z, a[2][2]); a[2][3] = fmaf(x2, gv.w, a[2][3]);
        a[3][0] = fmaf(x3, gv.x, a[3][0]); a[3][1] = fmaf(x3, gv.y, a[3][1]);
        a[3][2] = fmaf(x3, gv.z, a[3][2]); a[3][3] = fmaf(x3, gv.w, a[3][3]);
        a[4][0] = fmaf(x4, gv.x, a[4][0]); a[4][1] = fmaf(x4, gv.y, a[4][1]);
        a[4][2] = fmaf(x4, gv.z, a[4][2]); a[4][3] = fmaf(x4, gv.w, a[4][3]);
      }
      #pragma unroll
      for (int j = 0; j < 5; ++j)
        *(float4*)&s_xm[(grp * 25 + s0 + j) * 52 + o0] = make_float4(a[j][0], a[j][1], a[j][2], a[j][3]);
    }
    __syncthreads();
    if (act) {
      #pragma unroll 5
      for (int q = 0; q < 25; ++q) {
        const int sk = sk0 + q;
        float4 mv = *(const float4*)&s_xm[sk * 52 + o0];
        float w0 = s_w[(t0 + 0) * 132 + sk];
        float w1 = s_w[(t0 + 1) * 132 + sk];
        float w2 = s_w[(t0 + 2) * 132 + sk];
        float w3 = s_w[(t0 + 3) * 132 + sk];
        float w4 = s_w[(t0 + 4) * 132 + sk];
        acc2[0][0] = fmaf(w0, mv.x, acc2[0][0]); acc2[0][1] = fmaf(w0, mv.y, acc2[0][1]);
        acc2[0][2] = fmaf(w0, mv.z, acc2[0][2]); acc2[0][3] = fmaf(w0, mv.w, acc2[0][3]);
        acc2[1][0] = fmaf(w1, mv.x, acc2[1][0]); acc2[1][1] = fmaf(w1, mv.y, acc2[1][1]);
        acc2[1][2] = fmaf(w1, mv.z, acc2[1][2]); acc2[1][3] = fmaf(w1, mv.w, acc2[1][3]);
        acc2[2][0] = fmaf(w2, mv.x, acc2[2][0]); acc2[2][1] = fmaf(w2, mv.y, acc2[2][1]);
        acc2[2][2] = fmaf(w2, mv.z, acc2[2][2]); acc2[2][3] = fmaf(w2, mv.w, acc2[2][3]);
        acc2[3][0] = fmaf(w3, mv.x, acc2[3][0]); acc2[3][1] = fmaf(w3, mv.y, acc2[3][1]);
        acc2[3][2] = fmaf(w3, mv.z, acc2[3][2]); acc2[3][3] = fmaf(w3, mv.w, acc2[3][3]);
        acc2[4][0] = fmaf(w4, mv.x, acc2[4][0]); acc2[4][1] = fmaf(w4, mv.y, acc2[4][1]);
        acc2[4][2] = fmaf(w4, mv.z, acc2[4][2]); acc2[4][3] = fmaf(w4, mv.w, acc2[4][3]);
      }
    }
    __syncthreads();
  }

  if (act) {
    #pragma unroll
    for (int tt = 0; tt < 5; ++tt)
      *(float4*)&s_xm[grp * 1200 + (t0 + tt) * 48 + o0] =
          make_float4(acc2[tt][0], acc2[tt][1], acc2[tt][2], acc2[tt][3]);
    const int rs = tid / 12, ro0 = (tid % 12) * 4;
    float4 ra = make_float4(0.f, 0.f, 0.f, 0.f);
    const float* rp = root + ro0;
    #pragma unroll 4
    for (int i = 0; i < 32; ++i) {
      float4 rv = *(const float4*)(rp + i * 48);
      float xv = s_xT[i * 28 + rs];
      FMA4(ra, xv, rv)
    }
    *(float4*)&s_w[rs * 48 + ro0] = ra;
  }
  __syncthreads();
  if (act) {
    const int t = tid / 12, oe = (tid % 12) * 4;
    float4 p0 = *(const float4*)&s_xm[0 * 1200 + t * 48 + oe];
    float4 p1 = *(const float4*)&s_xm[1 * 1200 + t * 48 + oe];
    float4 p2 = *(const float4*)&s_xm[2 * 1200 + t * 48 + oe];
    float4 p3 = *(const float4*)&s_xm[3 * 1200 + t * 48 + oe];
    float4 p4 = *(const float4*)&s_xm[4 * 1200 + t * 48 + oe];
    float4 rt = *(const float4*)&s_w[t * 48 + oe];
    float idg = s_ideg[t];
    float4 bv = *(const float4*)&bias[oe];
    float4 v;
    v.x = fmaf(p0.x + p1.x + p2.x + p3.x + p4.x, idg, rt.x + bv.x);
    v.y = fmaf(p0.y + p1.y + p2.y + p3.y + p4.y, idg, rt.y + bv.y);
    v.z = fmaf(p0.z + p1.z + p2.z + p3.z + p4.z, idg, rt.z + bv.z);
    v.w = fmaf(p0.w + p1.w + p2.w + p3.w + p4.w, idg, rt.w + bv.w);
    *(float4*)&xout[b * 1200 + t * 48 + oe] =
        make_float4(eluf(v.x), eluf(v.y), eluf(v.z), eluf(v.w));
  }
}

// ---------------- conv3: adjacency + transposed-g3 vectorized xm build ----------------
__global__ __launch_bounds__(384) void conv3_kernel(
    const float* __restrict__ x, const float* __restrict__ pos,
    const float* __restrict__ g, const float* __restrict__ mu, const float* __restrict__ sig,
    const float* __restrict__ root, const float* __restrict__ bias,
    float* __restrict__ xout)
{
  const int b = blockIdx.x, tid = threadIdx.x;
  __shared__ float s_xm[75 * 28];
  __shared__ __align__(16) float s_x[75 * 16];
  __shared__ __align__(16) float s_g3T[25 * 16];   // [k][i] transposed
  __shared__ __align__(8) float s_pos[150];
  __shared__ float s_ek[125];
  __shared__ float s_ideg[75];
  __shared__ float s_out[75];
  __shared__ float s_r3[16];
  __shared__ unsigned char s_adj[75 * 76];
  __shared__ int s_cnt[75];

  if (tid < 150) s_pos[tid] = pos[b * 150 + tid];
  for (int e = tid; e < 1200; e += 384) s_x[e] = x[b * 1200 + e];
  for (int e = tid; e < 400; e += 384) { int k = e >> 4, i = e & 15; s_g3T[k * 16 + i] = g[i * 25 + k]; }
  if (tid < 25) {
    float m0 = mu[2 * tid], m1 = mu[2 * tid + 1];
    float sg0 = sig[2 * tid], sg1 = sig[2 * tid + 1];
    float n0 = NLOG2E_HALF / (sg0 * sg0 + 1e-15f);
    float n1 = NLOG2E_HALF / (sg1 * sg1 + 1e-15f);
    float c0 = 0.5f - m0, c1 = 0.5f - m1;
    s_ek[tid * 5 + 0] = n0;
    s_ek[tid * 5 + 1] = n1;
    s_ek[tid * 5 + 2] = 2.f * n0 * c0;
    s_ek[tid * 5 + 3] = 2.f * n1 * c1;
    s_ek[tid * 5 + 4] = n0 * c0 * c0 + n1 * c1 * c1;
  }
  if (tid < 16) s_r3[tid] = root[tid];
  if (tid < 75) s_out[tid] = 0.f;
  __syncthreads();

  // xm build: both operands via b128 (4+4 loads per task), sequential-i chain
  for (int e = tid; e < 1875; e += 384) {
    int s = e / 25, k = e % 25;
    float4 xa = *(const float4*)&s_x[s * 16];
    float4 xb = *(const float4*)&s_x[s * 16 + 4];
    float4 xc = *(const float4*)&s_x[s * 16 + 8];
    float4 xd = *(const float4*)&s_x[s * 16 + 12];
    float4 ga = *(const float4*)&s_g3T[k * 16];
    float4 gb = *(const float4*)&s_g3T[k * 16 + 4];
    float4 gc = *(const float4*)&s_g3T[k * 16 + 8];
    float4 gd = *(const float4*)&s_g3T[k * 16 + 12];
    float a = 0.f;
    a = fmaf(xa.x, ga.x, a); a = fmaf(xa.y, ga.y, a); a = fmaf(xa.z, ga.z, a); a = fmaf(xa.w, ga.w, a);
    a = fmaf(xb.x, gb.x, a); a = fmaf(xb.y, gb.y, a); a = fmaf(xb.z, gb.z, a); a = fmaf(xb.w, gb.w, a);
    a = fmaf(xc.x, gc.x, a); a = fmaf(xc.y, gc.y, a); a = fmaf(xc.z, gc.z, a); a = fmaf(xc.w, gc.w, a);
    a = fmaf(xd.x, gd.x, a); a = fmaf(xd.y, gd.y, a); a = fmaf(xd.z, gd.z, a); a = fmaf(xd.w, gd.w, a);
    s_xm[s * 28 + k] = a;
  }
  if (tid < 75) {
    int t = tid, c = 0;
    float pt0 = s_pos[t * 2], pt1 = s_pos[t * 2 + 1];
    for (int s = 0; s < 75; ++s) {
      if (s == t) continue;
      float d0 = pt0 - s_pos[s * 2]     + 1e-12f;
      float d1 = pt1 - s_pos[s * 2 + 1] + 1e-12f;
      if (d0 * d0 + d1 * d1 < 0.25f) s_adj[t * 76 + (c++)] = (unsigned char)s;
    }
    s_cnt[t] = c;
    s_ideg[t] = 1.f / (float)(c < 1 ? 1 : c);
  }
  __syncthreads();

  if (tid < 375) {
    const int t = tid / 5, kg = tid % 5;
    float n0[5], n1[5], e0[5], e1[5], f[5];
    #pragma unroll
    for (int j = 0; j < 5; ++j) {
      int k = kg * 5 + j;
      n0[j] = s_ek[k * 5 + 0]; n1[j] = s_ek[k * 5 + 1];
      e0[j] = s_ek[k * 5 + 2]; e1[j] = s_ek[k * 5 + 3];
      f[j]  = s_ek[k * 5 + 4];
    }
    const float pt0 = s_pos[t * 2], pt1 = s_pos[t * 2 + 1];
    const int cnt = s_cnt[t];
    const unsigned char* adj = &s_adj[t * 76];
    float acc5[5] = {0.f, 0.f, 0.f, 0.f, 0.f};
    for (int ii = 0; ii < cnt; ++ii) {
      int s = adj[ii];
      float2 pv = *(const float2*)&s_pos[s * 2];
      float ux = 2.f * (pt0 - pv.x);
      float uy = 2.f * (pt1 - pv.y);
      float u00 = ux * ux, u11 = uy * uy;
      const float* xmp = &s_xm[s * 28 + kg * 5];
      #pragma unroll
      for (int j = 0; j < 5; ++j) {
        float ar = fmaf(u00, n0[j], fmaf(u11, n1[j], fmaf(ux, e0[j], fmaf(uy, e1[j], f[j]))));
        acc5[j] = fmaf(exp2f(ar), xmp[j], acc5[j]);
      }
    }
    atomicAdd(&s_out[t], acc5[0] + acc5[1] + acc5[2] + acc5[3] + acc5[4]);
  }
  __syncthreads();

  if (tid < 75) {
    int t = tid;
    float r = 0.f;
    #pragma unroll
    for (int i = 0; i < 16; ++i) r = fmaf(s_x[t * 16 + i], s_r3[i], r);
    xout[b * 75 + t] = tanhf(s_out[t] * s_ideg[t] + r + bias[0]);
  }
}

// ---------------- MLP: 32 rows/block, aliased LDS 27.6KB ----------------
__global__ __launch_bounds__(256) void mlp_kernel(
    const float* __restrict__ pos_src, const float* __restrict__ feat,
    const float* __restrict__ w1, const float* __restrict__ b1,
    const float* __restrict__ w2, const float* __restrict__ b2,
    const float* __restrict__ w3, const float* __restrict__ b3,
    float* __restrict__ out, int fdim, int rep)
{
  const int tid = threadIdx.x;
  const int row0 = blockIdx.x * 32;
  const int din = fdim + 2;
  __shared__ __align__(16) char smem[27648];
  float* s_h1T = (float*)smem;             // [128][36]  18432B
  float* s_inT = (float*)(smem + 18432);   // [34][36]   (aliased with h2T)
  float* s_h2T = (float*)(smem + 18432);   // [64][36]   9216B

  if (tid < 64) {
    int r = tid >> 1, d = tid & 1;
    s_inT[d * 36 + r] = pos_src[((row0 + r) / rep) * 2 + d];
  }
  for (int e = tid; e < 32 * fdim; e += 256) {
    int r = e / fdim, c = e % fdim;
    s_inT[(2 + c) * 36 + r] = feat[(row0 + r) * fdim + c];
  }
  __syncthreads();

  const int rb = tid / 32, jb = tid % 32;
  {
    const int r0 = rb * 4, j0 = jb * 4;
    float acc[4][4];
    #pragma unroll
    for (int jj = 0; jj < 4; ++jj) {
      float bv = b1[j0 + jj];
      acc[0][jj] = bv; acc[1][jj] = bv; acc[2][jj] = bv; acc[3][jj] = bv;
    }
    for (int i = 0; i < din; ++i) {
      float4 xa = *(const float4*)&s_inT[i * 36 + r0];
      float4 wa = *(const float4*)&w1[i * 128 + j0];
      float wv[4] = {wa.x, wa.y, wa.z, wa.w};
      #pragma unroll
      for (int jj = 0; jj < 4; ++jj) {
        acc[0][jj] = fmaf(xa.x, wv[jj], acc[0][jj]);
        acc[1][jj] = fmaf(xa.y, wv[jj], acc[1][jj]);
        acc[2][jj] = fmaf(xa.z, wv[jj], acc[2][jj]);
        acc[3][jj] = fmaf(xa.w, wv[jj], acc[3][jj]);
      }
    }
    __syncthreads();
    #pragma unroll
    for (int jj = 0; jj < 4; ++jj)
      *(float4*)&s_h1T[(j0 + jj) * 36 + r0] =
        make_float4(eluf(acc[0][jj]), eluf(acc[1][jj]), eluf(acc[2][jj]), eluf(acc[3][jj]));
  }
  __syncthreads();

  {
    const int r0 = rb * 4, j0 = jb * 2;
    float acc[4][2];
    #pragma unroll
    for (int jj = 0; jj < 2; ++jj) {
      float bv = b2[j0 + jj];
      acc[0][jj] = bv; acc[1][jj] = bv; acc[2][jj] = bv; acc[3][jj] = bv;
    }
    #pragma unroll 4
    for (int i = 0; i < 128; ++i) {
      float4 ha = *(const float4*)&s_h1T[i * 36 + r0];
      float2 wa = *(const float2*)&w2[i * 64 + j0];
      float wv[2] = {wa.x, wa.y};
      #pragma unroll
      for (int jj = 0; jj < 2; ++jj) {
        acc[0][jj] = fmaf(ha.x, wv[jj], acc[0][jj]);
        acc[1][jj] = fmaf(ha.y, wv[jj], acc[1][jj]);
        acc[2][jj] = fmaf(ha.z, wv[jj], acc[2][jj]);
        acc[3][jj] = fmaf(ha.w, wv[jj], acc[3][jj]);
      }
    }
    #pragma unroll
    for (int jj = 0; jj < 2; ++jj)
      *(float4*)&s_h2T[(j0 + jj) * 36 + r0] =
        make_float4(eluf(acc[0][jj]), eluf(acc[1][jj]), eluf(acc[2][jj]), eluf(acc[3][jj]));
  }
  __syncthreads();

  if (tid < 64) {
    int r = tid >> 1, c = tid & 1;
    float a = b3[c];
    #pragma unroll 8
    for (int j = 0; j < 64; ++j)
      a = fmaf(s_h2T[j * 36 + r], w3[j * 2 + c], a);
    out[(row0 + r) * 2 + c] = eluf(a);
  }
}

extern "C" void kernel_launch(void* const* d_in, const int* in_sizes, int n_in,
                              void* d_out, int out_size, void* d_ws, size_t ws_size,
                              hipStream_t stream)
{
  const float* x     = (const float*)d_in[0];
  const float* pos   = (const float*)d_in[1];
  const float* g1    = (const float*)d_in[2];
  const float* mu1   = (const float*)d_in[3];
  const float* sig1  = (const float*)d_in[4];
  const float* root1 = (const float*)d_in[5];
  const float* cb1   = (const float*)d_in[6];
  const float* g2    = (const float*)d_in[7];
  const float* mu2   = (const float*)d_in[8];
  const float* sig2  = (const float*)d_in[9];
  const float* root2 = (const float*)d_in[10];
  const float* cb2   = (const float*)d_in[11];
  const float* g3    = (const float*)d_in[12];
  const float* mu3   = (const float*)d_in[13];
  const float* sig3  = (const float*)d_in[14];
  const float* root3 = (const float*)d_in[15];
  const float* cb3   = (const float*)d_in[16];
  const float* p1w1  = (const float*)d_in[17];
  const float* p1b1  = (const float*)d_in[18];
  const float* p1w2  = (const float*)d_in[19];
  const float* p1b2  = (const float*)d_in[20];
  const float* p1w3  = (const float*)d_in[21];
  const float* p1b3  = (const float*)d_in[22];
  const float* p2w1  = (const float*)d_in[23];
  const float* p2b1  = (const float*)d_in[24];
  const float* p2w2  = (const float*)d_in[25];
  const float* p2b2  = (const float*)d_in[26];
  const float* p2w3  = (const float*)d_in[27];
  const float* p2b3  = (const float*)d_in[28];

  float* out  = (float*)d_out;
  float* ws   = (float*)d_ws;
  float* x1   = ws;            // 5120*160 = 819200 floats
  float* pos1 = ws + 819200;   // 25600*2  = 51200
  float* x2   = ws + 870400;   // 76800*16 = 1228800
  float* x3   = out;           // 76800
  float* pos2 = out + 76800;   // 76800*2

  conv1_kernel<<<dim3(512), dim3(512), 0, stream>>>(x, pos, g1, mu1, sig1, root1, cb1, x1);
  mlp_kernel<<<dim3(800), dim3(256), 0, stream>>>(pos, x1, p1w1, p1b1, p1w2, p1b2, p1w3, p1b3,
                                                  pos1, 32, 5);
  conv2_kernel<<<dim3(1024), dim3(320), 0, stream>>>(x1, pos1, g2, mu2, sig2, root2, cb2, x2);
  mlp_kernel<<<dim3(2400), dim3(256), 0, stream>>>(pos1, x2, p2w1, p2b1, p2w2, p2b2, p2w3, p2b3,
                                                  pos2, 16, 3);
  conv3_kernel<<<dim3(1024), dim3(384), 0, stream>>>(x2, pos2, g3, mu3, sig3, root3, cb3, x3);
}

// Round 20
// 281.291 us; speedup vs baseline: 1.0068x; 1.0068x over previous
//
#include <hip/hip_runtime.h>
#include <math.h>

// GaussianGenerator v18 = round-16 best-measured build (281.97us).
// conv1=v4+vec-epilogue, conv2=v15 (root-GEMM mini-phase), conv3=adjacency@384,
// MLP=32-row aliased. All fp32 (pos chain is mask-critical).

__device__ __forceinline__ float eluf(float v) { return v > 0.f ? v : __expf(v) - 1.f; }

#define NLOG2E_HALF (-0.72134752f)   // -0.5*log2(e)

#define FMA4(A, S, V) \
  A.x = fmaf(S, V.x, A.x); A.y = fmaf(S, V.y, A.y); \
  A.z = fmaf(S, V.z, A.z); A.w = fmaf(S, V.w, A.w);

// ---------------- conv1: n=5, fin=64, K=25, cout=160; 2 graphs/block ----------------
__global__ __launch_bounds__(512) void conv1_kernel(
    const float* __restrict__ x, const float* __restrict__ pos,
    const float* __restrict__ g, const float* __restrict__ mu, const float* __restrict__ sig,
    const float* __restrict__ root, const float* __restrict__ bias,
    float* __restrict__ xout)
{
  const int b = blockIdx.x, tid = threadIdx.x;
  __shared__ __align__(16) float s_xT[64 * 12];
  __shared__ __align__(16) float s_xm[10 * 832];
  __shared__ __align__(16) float s_w[2 * 5 * 5 * 28];
  __shared__ __align__(16) float s_red[2 * 2 * 5 * 160];
  __shared__ float s_pos[20];
  __shared__ float s_msc[25][4];
  __shared__ float s_ideg[10];

  if (tid < 20) s_pos[tid] = pos[b * 20 + tid];
  if (tid < 25) {
    float m0 = mu[2 * tid], m1 = mu[2 * tid + 1];
    float s0 = sig[2 * tid], s1 = sig[2 * tid + 1];
    s_msc[tid][0] = 0.5f - m0;
    s_msc[tid][1] = 0.5f - m1;
    s_msc[tid][2] = NLOG2E_HALF / (s0 * s0 + 1e-15f);
    s_msc[tid][3] = NLOG2E_HALF / (s1 * s1 + 1e-15f);
  }
  for (int e = tid; e < 640; e += 512) { int nd = e >> 6, i = e & 63; s_xT[i * 12 + nd] = x[b * 640 + nd * 64 + i]; }
  for (int e = tid; e < 320; e += 512) { int r = e / 32, c = e % 32; s_xm[r * 832 + 800 + c] = 0.f; }
  __syncthreads();

  if (tid < 10) {
    int gg = tid / 5, t = tid % 5, c = 0;
    for (int s = 0; s < 5; ++s) {
      if (s == t) continue;
      float d0 = s_pos[(gg * 5 + t) * 2]     - s_pos[(gg * 5 + s) * 2]     + 1e-12f;
      float d1 = s_pos[(gg * 5 + t) * 2 + 1] - s_pos[(gg * 5 + s) * 2 + 1] + 1e-12f;
      c += (d0 * d0 + d1 * d1 < 0.25f) ? 1 : 0;
    }
    s_ideg[tid] = 1.f / (float)(c < 1 ? 1 : c);
  }
  for (int e = tid; e < 1400; e += 512) {
    int gg = e / 700, r2 = e % 700, t = r2 / 140, c = r2 % 140;
    int ch = c / 28, skl = c % 28;
    float wv = 0.f;
    if (skl < 25) {
      int kk = skl / 5, s = skl % 5, k = ch * 5 + kk;
      float d0 = s_pos[(gg * 5 + t) * 2]     - s_pos[(gg * 5 + s) * 2];
      float d1 = s_pos[(gg * 5 + t) * 2 + 1] - s_pos[(gg * 5 + s) * 2 + 1];
      float e0 = d0 + 1e-12f, e1 = d1 + 1e-12f;
      bool m = (e0 * e0 + e1 * e1 < 0.25f) && (s != t);
      float q0 = fmaf(2.f, d0, s_msc[k][0]);
      float q1 = fmaf(2.f, d1, s_msc[k][1]);
      float a = q0 * q0 * s_msc[k][2];
      a = fmaf(q1 * q1, s_msc[k][3], a);
      wv = m ? exp2f(a) : 0.f;
    }
    s_w[e] = wv;
  }
  __syncthreads();

  float sacc[5][2];
  #pragma unroll
  for (int t = 0; t < 5; ++t) { sacc[t][0] = 0.f; sacc[t][1] = 0.f; }
  const int sg = tid / 160, sr = tid % 160, sks = sr / 80, sob = sr % 80;
  const int so0 = sob * 2;

  for (int ch = 0; ch < 5; ++ch) {
    if (tid < 400) {
      const int c0 = tid * 2;
      const float* gp = g + ch * 800 + c0;
      float a[10][2];
      #pragma unroll
      for (int r = 0; r < 10; ++r) { a[r][0] = 0.f; a[r][1] = 0.f; }
      #pragma unroll 4
      for (int i = 0; i < 64; ++i) {
        float2 gv = *(const float2*)(gp + i * 4000);
        float4 xa = *(const float4*)&s_xT[i * 12];
        float4 xb = *(const float4*)&s_xT[i * 12 + 4];
        float2 xc = *(const float2*)&s_xT[i * 12 + 8];
        a[0][0] = fmaf(xa.x, gv.x, a[0][0]); a[0][1] = fmaf(xa.x, gv.y, a[0][1]);
        a[1][0] = fmaf(xa.y, gv.x, a[1][0]); a[1][1] = fmaf(xa.y, gv.y, a[1][1]);
        a[2][0] = fmaf(xa.z, gv.x, a[2][0]); a[2][1] = fmaf(xa.z, gv.y, a[2][1]);
        a[3][0] = fmaf(xa.w, gv.x, a[3][0]); a[3][1] = fmaf(xa.w, gv.y, a[3][1]);
        a[4][0] = fmaf(xb.x, gv.x, a[4][0]); a[4][1] = fmaf(xb.x, gv.y, a[4][1]);
        a[5][0] = fmaf(xb.y, gv.x, a[5][0]); a[5][1] = fmaf(xb.y, gv.y, a[5][1]);
        a[6][0] = fmaf(xb.z, gv.x, a[6][0]); a[6][1] = fmaf(xb.z, gv.y, a[6][1]);
        a[7][0] = fmaf(xb.w, gv.x, a[7][0]); a[7][1] = fmaf(xb.w, gv.y, a[7][1]);
        a[8][0] = fmaf(xc.x, gv.x, a[8][0]); a[8][1] = fmaf(xc.x, gv.y, a[8][1]);
        a[9][0] = fmaf(xc.y, gv.x, a[9][0]); a[9][1] = fmaf(xc.y, gv.y, a[9][1]);
      }
      #pragma unroll
      for (int r = 0; r < 10; ++r)
        *(float2*)&s_xm[r * 832 + c0] = make_float2(a[r][0], a[r][1]);
    }
    __syncthreads();
    if (tid < 320) {
#define C1_STEP(SK0) { \
      float2 m0 = *(const float2*)&s_xm[(sg * 5 + ((SK0) % 5)) * 832 + ((SK0) / 5) * 160 + so0]; \
      float2 m1 = *(const float2*)&s_xm[(sg * 5 + (((SK0) + 1) % 5)) * 832 + (((SK0) + 1) / 5) * 160 + so0]; \
      float2 m2 = *(const float2*)&s_xm[(sg * 5 + (((SK0) + 2) % 5)) * 832 + (((SK0) + 2) / 5) * 160 + so0]; \
      float2 m3 = *(const float2*)&s_xm[(sg * 5 + (((SK0) + 3) % 5)) * 832 + (((SK0) + 3) / 5) * 160 + so0]; \
      _Pragma("unroll") \
      for (int t = 0; t < 5; ++t) { \
        const float4 wv = *(const float4*)&s_w[((sg * 5 + t) * 5 + ch) * 28 + (SK0)]; \
        sacc[t][0] = fmaf(wv.x, m0.x, sacc[t][0]); sacc[t][1] = fmaf(wv.x, m0.y, sacc[t][1]); \
        sacc[t][0] = fmaf(wv.y, m1.x, sacc[t][0]); sacc[t][1] = fmaf(wv.y, m1.y, sacc[t][1]); \
        sacc[t][0] = fmaf(wv.z, m2.x, sacc[t][0]); sacc[t][1] = fmaf(wv.z, m2.y, sacc[t][1]); \
        sacc[t][0] = fmaf(wv.w, m3.x, sacc[t][0]); sacc[t][1] = fmaf(wv.w, m3.y, sacc[t][1]); \
      } }
      if (sks == 0) { C1_STEP(0) C1_STEP(4) C1_STEP(8) C1_STEP(12) }
      else          { C1_STEP(16) C1_STEP(20) C1_STEP(24) }
#undef C1_STEP
    }
    __syncthreads();
  }

  if (tid < 400) {
    const int rb = tid / 80, cb = tid % 80;
    const int r0 = rb * 2, c0 = cb * 2;
    float a00 = 0.f, a01 = 0.f, a10 = 0.f, a11 = 0.f;
    #pragma unroll 4
    for (int i = 0; i < 64; ++i) {
      float2 rv = *(const float2*)(root + i * 160 + c0);
      float2 xv = *(const float2*)&s_xT[i * 12 + r0];
      a00 = fmaf(xv.x, rv.x, a00); a01 = fmaf(xv.x, rv.y, a01);
      a10 = fmaf(xv.y, rv.x, a10); a11 = fmaf(xv.y, rv.y, a11);
    }
    *(float2*)&s_xm[r0 * 832 + c0]       = make_float2(a00, a01);
    *(float2*)&s_xm[(r0 + 1) * 832 + c0] = make_float2(a10, a11);
  }
  if (tid < 320) {
    #pragma unroll
    for (int t = 0; t < 5; ++t) {
      s_red[((sks * 2 + sg) * 5 + t) * 160 + so0]     = sacc[t][0];
      s_red[((sks * 2 + sg) * 5 + t) * 160 + so0 + 1] = sacc[t][1];
    }
  }
  __syncthreads();
  if (tid < 400) {
    const int gg = tid / 200, r2 = tid % 200, t = r2 / 40, oe = (r2 % 40) * 4;
    float4 p0 = *(const float4*)&s_red[((0 + gg) * 5 + t) * 160 + oe];
    float4 p1 = *(const float4*)&s_red[((2 + gg) * 5 + t) * 160 + oe];
    float4 rt = *(const float4*)&s_xm[(gg * 5 + t) * 832 + oe];
    float4 bv = *(const float4*)&bias[oe];
    float idg = s_ideg[gg * 5 + t];
    float4 v;
    v.x = fmaf(p0.x + p1.x, idg, rt.x + bv.x);
    v.y = fmaf(p0.y + p1.y, idg, rt.y + bv.y);
    v.z = fmaf(p0.z + p1.z, idg, rt.z + bv.z);
    v.w = fmaf(p0.w + p1.w, idg, rt.w + bv.w);
    *(float4*)&xout[b * 1600 + (gg * 5 + t) * 160 + oe] =
        make_float4(eluf(v.x), eluf(v.y), eluf(v.z), eluf(v.w));
  }
}

// ---------------- conv2 v15 (frozen): v4 + root-GEMM mini-phase ----------------
__global__ __launch_bounds__(320) void conv2_kernel(
    const float* __restrict__ x, const float* __restrict__ pos,
    const float* __restrict__ g, const float* __restrict__ mu, const float* __restrict__ sig,
    const float* __restrict__ root, const float* __restrict__ bias,
    float* __restrict__ xout)
{
  const int b = blockIdx.x, tid = threadIdx.x;
  __shared__ __align__(16) float s_xT[32 * 28];
  __shared__ __align__(16) float s_xm[125 * 52];
  __shared__ __align__(16) float s_w[25 * 132];
  __shared__ __align__(8)  float2 s_u[25 * 26];
  __shared__ float s_ek[25 * 5];
  __shared__ float s_ideg[25];

  const float* posb = pos + b * 50;
  if (tid < 25) {
    float m0 = mu[2 * tid], m1 = mu[2 * tid + 1];
    float sg0 = sig[2 * tid], sg1 = sig[2 * tid + 1];
    float n0 = NLOG2E_HALF / (sg0 * sg0 + 1e-15f);
    float n1 = NLOG2E_HALF / (sg1 * sg1 + 1e-15f);
    float c0 = 0.5f - m0, c1 = 0.5f - m1;
    s_ek[tid * 5 + 0] = n0;
    s_ek[tid * 5 + 1] = n1;
    s_ek[tid * 5 + 2] = 2.f * n0 * c0;
    s_ek[tid * 5 + 3] = 2.f * n1 * c1;
    s_ek[tid * 5 + 4] = fmaf(n0, c0 * c0, n1 * c1 * c1);
  }
  for (int e = tid; e < 800; e += 320) { int r = e / 32, i = e % 32; s_xT[i * 28 + r] = x[b * 800 + e]; }
  __syncthreads();

  for (int e = tid; e < 625; e += 320) {
    int t = e / 25, s = e % 25;
    float d0 = posb[t * 2]     - posb[s * 2];
    float d1 = posb[t * 2 + 1] - posb[s * 2 + 1];
    float e0 = d0 + 1e-12f, e1 = d1 + 1e-12f;
    bool m = (e0 * e0 + e1 * e1 < 0.25f) && (s != t);
    s_u[t * 26 + s] = m ? make_float2(2.f * d0, 2.f * d1) : make_float2(1e18f, 0.f);
  }
  if (tid < 25) {
    int t = tid, c = 0;
    for (int s = 0; s < 25; ++s) {
      if (s == t) continue;
      float d0 = posb[t * 2]     - posb[s * 2]     + 1e-12f;
      float d1 = posb[t * 2 + 1] - posb[s * 2 + 1] + 1e-12f;
      c += (d0 * d0 + d1 * d1 < 0.25f) ? 1 : 0;
    }
    s_ideg[t] = 1.f / (float)(c < 1 ? 1 : c);
  }
  __syncthreads();

  const bool act = tid < 300;
  const int grp = tid / 60, rr = tid % 60, tg = rr / 12, og = rr % 12;
  const int o0 = og * 4;
  const int t0 = tg * 5, sk0 = grp * 25, s0 = tg * 5;

  float acc2[5][4];
  #pragma unroll
  for (int tt = 0; tt < 5; ++tt) { acc2[tt][0] = acc2[tt][1] = acc2[tt][2] = acc2[tt][3] = 0.f; }

  for (int ch = 0; ch < 5; ++ch) {
    const int k0 = ch * 5;
    for (int e = tid; e < 3125; e += 320) {
      int t = e / 125, c = e % 125;
      int kk = c / 25, s = c % 25, k = k0 + kk;
      float2 uv = s_u[t * 26 + s];
      const float* ekp = &s_ek[k * 5];
      float ar = fmaf(uv.x * uv.x, ekp[0],
                 fmaf(uv.y * uv.y, ekp[1],
                 fmaf(uv.x, ekp[2],
                 fmaf(uv.y, ekp[3], ekp[4]))));
      s_w[t * 132 + c] = exp2f(ar);
    }
    if (act) {
      const float* gp = g + (k0 + grp) * 48 + o0;
      float a[5][4];
      #pragma unroll
      for (int r = 0; r < 5; ++r) { a[r][0] = a[r][1] = a[r][2] = a[r][3] = 0.f; }
      #pragma unroll 4
      for (int i = 0; i < 32; ++i) {
        float4 gv = *(const float4*)(gp + i * 1200);
        float x0 = s_xT[i * 28 + s0];
        float x1 = s_xT[i * 28 + s0 + 1];
        float x2 = s_xT[i * 28 + s0 + 2];
        float x3 = s_xT[i * 28 + s0 + 3];
        float x4 = s_xT[i * 28 + s0 + 4];
        a[0][0] = fmaf(x0, gv.x, a[0][0]); a[0][1] = fmaf(x0, gv.y, a[0][1]);
        a[0][2] = fmaf(x0, gv.z, a[0][2]); a[0][3] = fmaf(x0, gv.w, a[0][3]);
        a[1][0] = fmaf(x1, gv.x, a[1][0]); a[1][1] = fmaf(x1, gv.y, a[1][1]);
        a[1][2] = fmaf(x1, gv.z, a[1][2]); a[1][3] = fmaf(x1, gv.w, a[1][3]);
        a[2][0] = fmaf(x2, gv.x, a[2][0]); a[2][1] = fmaf(x2, gv.y, a[2][1]);
        a[2][2] = fmaf(x2, gv.z, a[2][2]); a[2][3] = fmaf(x2, gv.w, a[2][3]);
        a[3][0] = fmaf(x3, gv.x, a[3][0]); a[3][1] = fmaf(x3, gv.y, a[3][1]);
        a[3][2] = fmaf(x3, gv.z, a[3][2]); a[3][3] = fmaf(x3, gv.w, a[3][3]);
        a[4][0] = fmaf(x4, gv.x, a[4][0]); a[4][1] = fmaf(x4, gv.y, a[4][1]);
        a[4][2] = fmaf(x4, gv.z, a[4][2]); a[4][3] = fmaf(x4, gv.w, a[4][3]);
      }
      #pragma unroll
      for (int j = 0; j < 5; ++j)
        *(float4*)&s_xm[(grp * 25 + s0 + j) * 52 + o0] = make_float4(a[j][0], a[j][1], a[j][2], a[j][3]);
    }
    __syncthreads();
    if (act) {
      #pragma unroll 5
      for (int q = 0; q < 25; ++q) {
        const int sk = sk0 + q;
        float4 mv = *(const float4*)&s_xm[sk * 52 + o0];
        float w0 = s_w[(t0 + 0) * 132 + sk];
        float w1 = s_w[(t0 + 1) * 132 + sk];
        float w2 = s_w[(t0 + 2) * 132 + sk];
        float w3 = s_w[(t0 + 3) * 132 + sk];
        float w4 = s_w[(t0 + 4) * 132 + sk];
        acc2[0][0] = fmaf(w0, mv.x, acc2[0][0]); acc2[0][1] = fmaf(w0, mv.y, acc2[0][1]);
        acc2[0][2] = fmaf(w0, mv.z, acc2[0][2]); acc2[0][3] = fmaf(w0, mv.w, acc2[0][3]);
        acc2[1][0] = fmaf(w1, mv.x, acc2[1][0]); acc2[1][1] = fmaf(w1, mv.y, acc2[1][1]);
        acc2[1][2] = fmaf(w1, mv.z, acc2[1][2]); acc2[1][3] = fmaf(w1, mv.w, acc2[1][3]);
        acc2[2][0] = fmaf(w2, mv.x, acc2[2][0]); acc2[2][1] = fmaf(w2, mv.y, acc2[2][1]);
        acc2[2][2] = fmaf(w2, mv.z, acc2[2][2]); acc2[2][3] = fmaf(w2, mv.w, acc2[2][3]);
        acc2[3][0] = fmaf(w3, mv.x, acc2[3][0]); acc2[3][1] = fmaf(w3, mv.y, acc2[3][1]);
        acc2[3][2] = fmaf(w3, mv.z, acc2[3][2]); acc2[3][3] = fmaf(w3, mv.w, acc2[3][3]);
        acc2[4][0] = fmaf(w4, mv.x, acc2[4][0]); acc2[4][1] = fmaf(w4, mv.y, acc2[4][1]);
        acc2[4][2] = fmaf(w4, mv.z, acc2[4][2]); acc2[4][3] = fmaf(w4, mv.w, acc2[4][3]);
      }
    }
    __syncthreads();
  }

  if (act) {
    #pragma unroll
    for (int tt = 0; tt < 5; ++tt)
      *(float4*)&s_xm[grp * 1200 + (t0 + tt) * 48 + o0] =
          make_float4(acc2[tt][0], acc2[tt][1], acc2[tt][2], acc2[tt][3]);
    const int rs = tid / 12, ro0 = (tid % 12) * 4;
    float4 ra = make_float4(0.f, 0.f, 0.f, 0.f);
    const float* rp = root + ro0;
    #pragma unroll 4
    for (int i = 0; i < 32; ++i) {
      float4 rv = *(const float4*)(rp + i * 48);
      float xv = s_xT[i * 28 + rs];
      FMA4(ra, xv, rv)
    }
    *(float4*)&s_w[rs * 48 + ro0] = ra;
  }
  __syncthreads();
  if (act) {
    const int t = tid / 12, oe = (tid % 12) * 4;
    float4 p0 = *(const float4*)&s_xm[0 * 1200 + t * 48 + oe];
    float4 p1 = *(const float4*)&s_xm[1 * 1200 + t * 48 + oe];
    float4 p2 = *(const float4*)&s_xm[2 * 1200 + t * 48 + oe];
    float4 p3 = *(const float4*)&s_xm[3 * 1200 + t * 48 + oe];
    float4 p4 = *(const float4*)&s_xm[4 * 1200 + t * 48 + oe];
    float4 rt = *(const float4*)&s_w[t * 48 + oe];
    float idg = s_ideg[t];
    float4 bv = *(const float4*)&bias[oe];
    float4 v;
    v.x = fmaf(p0.x + p1.x + p2.x + p3.x + p4.x, idg, rt.x + bv.x);
    v.y = fmaf(p0.y + p1.y + p2.y + p3.y + p4.y, idg, rt.y + bv.y);
    v.z = fmaf(p0.z + p1.z + p2.z + p3.z + p4.z, idg, rt.z + bv.z);
    v.w = fmaf(p0.w + p1.w + p2.w + p3.w + p4.w, idg, rt.w + bv.w);
    *(float4*)&xout[b * 1200 + t * 48 + oe] =
        make_float4(eluf(v.x), eluf(v.y), eluf(v.z), eluf(v.w));
  }
}

// ---------------- conv3: compact adjacency; n=75, fin=16, K=25, tanh ----------------
__global__ __launch_bounds__(384) void conv3_kernel(
    const float* __restrict__ x, const float* __restrict__ pos,
    const float* __restrict__ g, const float* __restrict__ mu, const float* __restrict__ sig,
    const float* __restrict__ root, const float* __restrict__ bias,
    float* __restrict__ xout)
{
  const int b = blockIdx.x, tid = threadIdx.x;
  __shared__ float s_xm[75 * 28];
  __shared__ float s_x[75 * 16];
  __shared__ float s_g3[400];
  __shared__ __align__(8) float s_pos[150];
  __shared__ float s_ek[125];
  __shared__ float s_ideg[75];
  __shared__ float s_out[75];
  __shared__ float s_r3[16];
  __shared__ unsigned char s_adj[75 * 76];
  __shared__ int s_cnt[75];

  if (tid < 150) s_pos[tid] = pos[b * 150 + tid];
  for (int e = tid; e < 1200; e += 384) s_x[e] = x[b * 1200 + e];
  for (int e = tid; e < 400; e += 384) s_g3[e] = g[e];
  if (tid < 25) {
    float m0 = mu[2 * tid], m1 = mu[2 * tid + 1];
    float sg0 = sig[2 * tid], sg1 = sig[2 * tid + 1];
    float n0 = NLOG2E_HALF / (sg0 * sg0 + 1e-15f);
    float n1 = NLOG2E_HALF / (sg1 * sg1 + 1e-15f);
    float c0 = 0.5f - m0, c1 = 0.5f - m1;
    s_ek[tid * 5 + 0] = n0;
    s_ek[tid * 5 + 1] = n1;
    s_ek[tid * 5 + 2] = 2.f * n0 * c0;
    s_ek[tid * 5 + 3] = 2.f * n1 * c1;
    s_ek[tid * 5 + 4] = n0 * c0 * c0 + n1 * c1 * c1;
  }
  if (tid < 16) s_r3[tid] = root[tid];
  if (tid < 75) s_out[tid] = 0.f;
  __syncthreads();

  for (int e = tid; e < 1875; e += 384) {
    int s = e / 25, k = e % 25;
    float a = 0.f;
    #pragma unroll
    for (int i = 0; i < 16; ++i) a = fmaf(s_x[s * 16 + i], s_g3[i * 25 + k], a);
    s_xm[s * 28 + k] = a;
  }
  if (tid < 75) {
    int t = tid, c = 0;
    float pt0 = s_pos[t * 2], pt1 = s_pos[t * 2 + 1];
    for (int s = 0; s < 75; ++s) {
      if (s == t) continue;
      float d0 = pt0 - s_pos[s * 2]     + 1e-12f;
      float d1 = pt1 - s_pos[s * 2 + 1] + 1e-12f;
      if (d0 * d0 + d1 * d1 < 0.25f) s_adj[t * 76 + (c++)] = (unsigned char)s;
    }
    s_cnt[t] = c;
    s_ideg[t] = 1.f / (float)(c < 1 ? 1 : c);
  }
  __syncthreads();

  if (tid < 375) {
    const int t = tid / 5, kg = tid % 5;
    float n0[5], n1[5], e0[5], e1[5], f[5];
    #pragma unroll
    for (int j = 0; j < 5; ++j) {
      int k = kg * 5 + j;
      n0[j] = s_ek[k * 5 + 0]; n1[j] = s_ek[k * 5 + 1];
      e0[j] = s_ek[k * 5 + 2]; e1[j] = s_ek[k * 5 + 3];
      f[j]  = s_ek[k * 5 + 4];
    }
    const float pt0 = s_pos[t * 2], pt1 = s_pos[t * 2 + 1];
    const int cnt = s_cnt[t];
    const unsigned char* adj = &s_adj[t * 76];
    float acc5[5] = {0.f, 0.f, 0.f, 0.f, 0.f};
    for (int ii = 0; ii < cnt; ++ii) {
      int s = adj[ii];
      float2 pv = *(const float2*)&s_pos[s * 2];
      float ux = 2.f * (pt0 - pv.x);
      float uy = 2.f * (pt1 - pv.y);
      float u00 = ux * ux, u11 = uy * uy;
      const float* xmp = &s_xm[s * 28 + kg * 5];
      #pragma unroll
      for (int j = 0; j < 5; ++j) {
        float ar = fmaf(u00, n0[j], fmaf(u11, n1[j], fmaf(ux, e0[j], fmaf(uy, e1[j], f[j]))));
        acc5[j] = fmaf(exp2f(ar), xmp[j], acc5[j]);
      }
    }
    atomicAdd(&s_out[t], acc5[0] + acc5[1] + acc5[2] + acc5[3] + acc5[4]);
  }
  __syncthreads();

  if (tid < 75) {
    int t = tid;
    float r = 0.f;
    #pragma unroll
    for (int i = 0; i < 16; ++i) r = fmaf(s_x[t * 16 + i], s_r3[i], r);
    xout[b * 75 + t] = tanhf(s_out[t] * s_ideg[t] + r + bias[0]);
  }
}

// ---------------- MLP: 32 rows/block, aliased LDS 27.6KB ----------------
__global__ __launch_bounds__(256) void mlp_kernel(
    const float* __restrict__ pos_src, const float* __restrict__ feat,
    const float* __restrict__ w1, const float* __restrict__ b1,
    const float* __restrict__ w2, const float* __restrict__ b2,
    const float* __restrict__ w3, const float* __restrict__ b3,
    float* __restrict__ out, int fdim, int rep)
{
  const int tid = threadIdx.x;
  const int row0 = blockIdx.x * 32;
  const int din = fdim + 2;
  __shared__ __align__(16) char smem[27648];
  float* s_h1T = (float*)smem;             // [128][36]  18432B
  float* s_inT = (float*)(smem + 18432);   // [34][36]   (aliased with h2T)
  float* s_h2T = (float*)(smem + 18432);   // [64][36]   9216B

  if (tid < 64) {
    int r = tid >> 1, d = tid & 1;
    s_inT[d * 36 + r] = pos_src[((row0 + r) / rep) * 2 + d];
  }
  for (int e = tid; e < 32 * fdim; e += 256) {
    int r = e / fdim, c = e % fdim;
    s_inT[(2 + c) * 36 + r] = feat[(row0 + r) * fdim + c];
  }
  __syncthreads();

  const int rb = tid / 32, jb = tid % 32;
  {
    const int r0 = rb * 4, j0 = jb * 4;
    float acc[4][4];
    #pragma unroll
    for (int jj = 0; jj < 4; ++jj) {
      float bv = b1[j0 + jj];
      acc[0][jj] = bv; acc[1][jj] = bv; acc[2][jj] = bv; acc[3][jj] = bv;
    }
    for (int i = 0; i < din; ++i) {
      float4 xa = *(const float4*)&s_inT[i * 36 + r0];
      float4 wa = *(const float4*)&w1[i * 128 + j0];
      float wv[4] = {wa.x, wa.y, wa.z, wa.w};
      #pragma unroll
      for (int jj = 0; jj < 4; ++jj) {
        acc[0][jj] = fmaf(xa.x, wv[jj], acc[0][jj]);
        acc[1][jj] = fmaf(xa.y, wv[jj], acc[1][jj]);
        acc[2][jj] = fmaf(xa.z, wv[jj], acc[2][jj]);
        acc[3][jj] = fmaf(xa.w, wv[jj], acc[3][jj]);
      }
    }
    __syncthreads();
    #pragma unroll
    for (int jj = 0; jj < 4; ++jj)
      *(float4*)&s_h1T[(j0 + jj) * 36 + r0] =
        make_float4(eluf(acc[0][jj]), eluf(acc[1][jj]), eluf(acc[2][jj]), eluf(acc[3][jj]));
  }
  __syncthreads();

  {
    const int r0 = rb * 4, j0 = jb * 2;
    float acc[4][2];
    #pragma unroll
    for (int jj = 0; jj < 2; ++jj) {
      float bv = b2[j0 + jj];
      acc[0][jj] = bv; acc[1][jj] = bv; acc[2][jj] = bv; acc[3][jj] = bv;
    }
    #pragma unroll 4
    for (int i = 0; i < 128; ++i) {
      float4 ha = *(const float4*)&s_h1T[i * 36 + r0];
      float2 wa = *(const float2*)&w2[i * 64 + j0];
      float wv[2] = {wa.x, wa.y};
      #pragma unroll
      for (int jj = 0; jj < 2; ++jj) {
        acc[0][jj] = fmaf(ha.x, wv[jj], acc[0][jj]);
        acc[1][jj] = fmaf(ha.y, wv[jj], acc[1][jj]);
        acc[2][jj] = fmaf(ha.z, wv[jj], acc[2][jj]);
        acc[3][jj] = fmaf(ha.w, wv[jj], acc[3][jj]);
      }
    }
    #pragma unroll
    for (int jj = 0; jj < 2; ++jj)
      *(float4*)&s_h2T[(j0 + jj) * 36 + r0] =
        make_float4(eluf(acc[0][jj]), eluf(acc[1][jj]), eluf(acc[2][jj]), eluf(acc[3][jj]));
  }
  __syncthreads();

  if (tid < 64) {
    int r = tid >> 1, c = tid & 1;
    float a = b3[c];
    #pragma unroll 8
    for (int j = 0; j < 64; ++j)
      a = fmaf(s_h2T[j * 36 + r], w3[j * 2 + c], a);
    out[(row0 + r) * 2 + c] = eluf(a);
  }
}

extern "C" void kernel_launch(void* const* d_in, const int* in_sizes, int n_in,
                              void* d_out, int out_size, void* d_ws, size_t ws_size,
                              hipStream_t stream)
{
  const float* x     = (const float*)d_in[0];
  const float* pos   = (const float*)d_in[1];
  const float* g1    = (const float*)d_in[2];
  const float* mu1   = (const float*)d_in[3];
  const float* sig1  = (const float*)d_in[4];
  const float* root1 = (const float*)d_in[5];
  const float* cb1   = (const float*)d_in[6];
  const float* g2    = (const float*)d_in[7];
  const float* mu2   = (const float*)d_in[8];
  const float* sig2  = (const float*)d_in[9];
  const float* root2 = (const float*)d_in[10];
  const float* cb2   = (const float*)d_in[11];
  const float* g3    = (const float*)d_in[12];
  const float* mu3   = (const float*)d_in[13];
  const float* sig3  = (const float*)d_in[14];
  const float* root3 = (const float*)d_in[15];
  const float* cb3   = (const float*)d_in[16];
  const float* p1w1  = (const float*)d_in[17];
  const float* p1b1  = (const float*)d_in[18];
  const float* p1w2  = (const float*)d_in[19];
  const float* p1b2  = (const float*)d_in[20];
  const float* p1w3  = (const float*)d_in[21];
  const float* p1b3  = (const float*)d_in[22];
  const float* p2w1  = (const float*)d_in[23];
  const float* p2b1  = (const float*)d_in[24];
  const float* p2w2  = (const float*)d_in[25];
  const float* p2b2  = (const float*)d_in[26];
  const float* p2w3  = (const float*)d_in[27];
  const float* p2b3  = (const float*)d_in[28];

  float* out  = (float*)d_out;
  float* ws   = (float*)d_ws;
  float* x1   = ws;            // 5120*160 = 819200 floats
  float* pos1 = ws + 819200;   // 25600*2  = 51200
  float* x2   = ws + 870400;   // 76800*16 = 1228800
  float* x3   = out;           // 76800
  float* pos2 = out + 76800;   // 76800*2

  conv1_kernel<<<dim3(512), dim3(512), 0, stream>>>(x, pos, g1, mu1, sig1, root1, cb1, x1);
  mlp_kernel<<<dim3(800), dim3(256), 0, stream>>>(pos, x1, p1w1, p1b1, p1w2, p1b2, p1w3, p1b3,
                                                  pos1, 32, 5);
  conv2_kernel<<<dim3(1024), dim3(320), 0, stream>>>(x1, pos1, g2, mu2, sig2, root2, cb2, x2);
  mlp_kernel<<<dim3(2400), dim3(256), 0, stream>>>(pos1, x2, p2w1, p2b1, p2w2, p2b2, p2w3, p2b3,
                                                  pos2, 16, 3);
  conv3_kernel<<<dim3(1024), dim3(384), 0, stream>>>(x2, pos2, g3, mu3, sig3, root3, cb3, x3);
}